// Round 2
// baseline (1812.239 us; speedup 1.0000x reference)
//
#include <hip/hip_runtime.h>

// GRU fused, round 2: 3-way gate-row split.
// Thread = (batch bl in 0..3, gate-row row in 0..143); owns one row of
// [W_hh | W_ih] (54 floats) in registers -> no spill (round 1 had 144 weight
// regs vs VGPR_Count=128 => AGPR spill, ~2x VALU overhead).
// 512 blocks x 576 threads = 4608 waves = 4.5/SIMD (round 1: 1.5 ragged).
// Mapping tid = row*4 + bl makes gate branches wave-uniform:
//   waves 0-2 gate r (combiners), 3-5 gate z, 6-8 gate n.
// Per step: dot(54 FMA, LDS-broadcast h) -> write pre (SoA LDS) -> bar ->
// combine on waves 0-2 (sigmoid/tanh, h update, h_hist write) -> bar.
// FC fused every 8 steps from h_hist window; x staged per window with
// register prefetch of the next window.

namespace {

constexpr int T = 1024;
constexpr int D = 6;
constexpr int H = 48;
constexpr int R = 3 * H;          // 144 gate rows
constexpr int NB = 4;             // batches per block
constexpr int BLOCK = NB * R;     // 576 threads = 9 waves
constexpr int W = 8;              // h-history window for fused FC
constexpr int HP = 52;            // h_hist stride (floats): 16B-aligned rows
constexpr int PP = 49;            // pre stride (floats): odd -> <=2-way banks

__device__ __forceinline__ float fexp2(float x) { return __builtin_amdgcn_exp2f(x); }
__device__ __forceinline__ float frcp(float x) { return __builtin_amdgcn_rcpf(x); }
__device__ __forceinline__ float sigmoid_f(float x) {
  return frcp(1.0f + fexp2(-1.44269504088896340736f * x));
}
__device__ __forceinline__ float tanh_f(float x) {
  float e = fexp2(2.88539008177792681472f * x);
  return 1.0f - 2.0f * frcp(e + 1.0f);
}

__global__ __launch_bounds__(BLOCK, 5) void gru_fused(
    const float* __restrict__ x, const float* __restrict__ W_ih,
    const float* __restrict__ W_hh, const float* __restrict__ b_ih,
    const float* __restrict__ b_hh, const float* __restrict__ fc_w,
    const float* __restrict__ fc_b, float* __restrict__ y) {

  __shared__ float h_hist[W][NB][HP];
  __shared__ float pre[3][NB][PP];   // [0]=gh_n+b_hn, [1]=gi_n+b_in, [2]=pre_z
  __shared__ float xs[NB][W * D];    // x window, 48 floats per batch
  __shared__ float fcw_s[D][H];

  const int tid  = threadIdx.x;
  const int row  = tid >> 2;         // 0..143  (NB==4)
  const int bl   = tid & 3;          // local batch
  const int gate = row / H;          // 0=r 1=z 2=n   (wave-uniform)
  const int u    = row - gate * H;   // unit 0..47

  // init LDS
  for (int i = tid; i < W * NB * HP; i += BLOCK) (&h_hist[0][0][0])[i] = 0.0f;
  for (int i = tid; i < D * H; i += BLOCK) (&fcw_s[0][0])[i] = fc_w[i];

  // own row of W_hh (48) + W_ih (6) + biases
  float4 wh[12];
#pragma unroll
  for (int j = 0; j < 12; ++j) wh[j] = *(const float4*)(W_hh + row * H + 4 * j);
  float wi[6];
#pragma unroll
  for (int d = 0; d < 6; ++d) wi[d] = W_ih[row * D + d];
  const float bi = b_ih[row], bh = b_hh[row];

  const size_t bB = (size_t)blockIdx.x * NB;

  // x stager mapping (tid<192): 48 contiguous floats per batch per window
  const int sb = tid / 48, si = tid - sb * 48;
  const float* xsrc = x + (bB + sb) * (size_t)T * D;

  // FC mapping (tid<192): (batch yb, timestep yts, out dim yd)
  const int yb = tid / 48, yr = tid - yb * 48, yts = yr / D, yd = yr - yts * D;
  const float fcb = fc_b[yd];
  float* ydst = y + ((bB + yb) * (size_t)T) * D + yd;

  float xreg = 0.0f;
  if (tid < 192) xreg = xsrc[si];    // window 0

  float hreg = 0.0f;                 // combiner-owned h (gate==0 threads)

  for (int t0 = 0; t0 < T; t0 += W) {
    if (tid < 192) {
      xs[sb][si] = xreg;
      if (t0 + W < T) xreg = xsrc[(t0 + W) * D + si];  // prefetch next window
    }
    __syncthreads();

#pragma unroll
    for (int tw = 0; tw < W; ++tw) {
      const int p = (tw + W - 1) & (W - 1);
      // 4-accumulator dot: h broadcast from LDS (4 distinct addrs/wave,
      // disjoint bank quads), weights in regs
      const float4* hv = (const float4*)(&h_hist[p][bl][0]);
      float a0 = 0.f, a1 = 0.f, a2 = 0.f, a3 = 0.f;
#pragma unroll
      for (int j = 0; j < 12; j += 4) {
        const float4 h0 = hv[j], h1 = hv[j + 1], h2 = hv[j + 2], h3 = hv[j + 3];
        a0 = fmaf(wh[j].x, h0.x, a0);     a0 = fmaf(wh[j].y, h0.y, a0);
        a0 = fmaf(wh[j].z, h0.z, a0);     a0 = fmaf(wh[j].w, h0.w, a0);
        a1 = fmaf(wh[j + 1].x, h1.x, a1); a1 = fmaf(wh[j + 1].y, h1.y, a1);
        a1 = fmaf(wh[j + 1].z, h1.z, a1); a1 = fmaf(wh[j + 1].w, h1.w, a1);
        a2 = fmaf(wh[j + 2].x, h2.x, a2); a2 = fmaf(wh[j + 2].y, h2.y, a2);
        a2 = fmaf(wh[j + 2].z, h2.z, a2); a2 = fmaf(wh[j + 2].w, h2.w, a2);
        a3 = fmaf(wh[j + 3].x, h3.x, a3); a3 = fmaf(wh[j + 3].y, h3.y, a3);
        a3 = fmaf(wh[j + 3].z, h3.z, a3); a3 = fmaf(wh[j + 3].w, h3.w, a3);
      }
      const float dh = (a0 + a1) + (a2 + a3);
      const float2* xv = (const float2*)(&xs[bl][tw * D]);
      const float2 x0 = xv[0], x1 = xv[1], x2 = xv[2];
      float dx = wi[0] * x0.x;
      dx = fmaf(wi[1], x0.y, dx); dx = fmaf(wi[2], x1.x, dx);
      dx = fmaf(wi[3], x1.y, dx); dx = fmaf(wi[4], x2.x, dx);
      dx = fmaf(wi[5], x2.y, dx);

      float myr = 0.0f;
      if (gate == 0) {
        myr = dh + dx + bi + bh;               // pre_r stays in register
      } else if (gate == 1) {
        pre[2][bl][u] = dh + dx + bi + bh;     // pre_z
      } else {
        pre[0][bl][u] = dh + bh;               // gh_n + b_hn (r multiplies this)
        pre[1][bl][u] = dx + bi;               // gi_n + b_in
      }
      __syncthreads();

      if (gate == 0) {                         // waves 0-2 only
        const float nh  = pre[0][bl][u];
        const float gin = pre[1][bl][u];
        const float pz  = pre[2][bl][u];
        const float r = sigmoid_f(myr);
        const float z = sigmoid_f(pz);
        const float n = tanh_f(gin + r * nh);
        hreg = fmaf(z, hreg - n, n);           // (1-z)n + z h
        h_hist[tw][bl][u] = hreg;
      }
      __syncthreads();
    }

    // fused FC over the window: one output per thread, waves 0-2
    if (tid < 192) {
      const float4* hv = (const float4*)(&h_hist[yts][yb][0]);
      const float4* fv = (const float4*)(&fcw_s[yd][0]);
      float f0 = fcb, f1 = 0.f, f2 = 0.f, f3 = 0.f;
#pragma unroll
      for (int j = 0; j < 12; j += 4) {
        const float4 h0 = hv[j], h1 = hv[j + 1], h2 = hv[j + 2], h3 = hv[j + 3];
        const float4 w0 = fv[j], w1 = fv[j + 1], w2 = fv[j + 2], w3 = fv[j + 3];
        f0 = fmaf(w0.x, h0.x, f0); f0 = fmaf(w0.y, h0.y, f0);
        f0 = fmaf(w0.z, h0.z, f0); f0 = fmaf(w0.w, h0.w, f0);
        f1 = fmaf(w1.x, h1.x, f1); f1 = fmaf(w1.y, h1.y, f1);
        f1 = fmaf(w1.z, h1.z, f1); f1 = fmaf(w1.w, h1.w, f1);
        f2 = fmaf(w2.x, h2.x, f2); f2 = fmaf(w2.y, h2.y, f2);
        f2 = fmaf(w2.z, h2.z, f2); f2 = fmaf(w2.w, h2.w, f2);
        f3 = fmaf(w3.x, h3.x, f3); f3 = fmaf(w3.y, h3.y, f3);
        f3 = fmaf(w3.z, h3.z, f3); f3 = fmaf(w3.w, h3.w, f3);
      }
      ydst[(t0 + yts) * D] = (f0 + f1) + (f2 + f3);
    }
    // no barrier needed here: next iteration writes xs (readers of xs are
    // past step-7's combine barrier), then barriers before the next dots;
    // FC's h_hist reads are separated from the next combine-write of
    // h_hist[0] by that barrier + dot + barrier.
  }
}

}  // namespace

extern "C" void kernel_launch(void* const* d_in, const int* in_sizes, int n_in,
                              void* d_out, int out_size, void* d_ws, size_t ws_size,
                              hipStream_t stream) {
  const float* x    = (const float*)d_in[0];
  const float* W_ih = (const float*)d_in[1];
  const float* W_hh = (const float*)d_in[2];
  const float* b_ih = (const float*)d_in[3];
  const float* b_hh = (const float*)d_in[4];
  const float* fc_w = (const float*)d_in[5];
  const float* fc_b = (const float*)d_in[6];
  float* y = (float*)d_out;

  constexpr int B = 2048;
  gru_fused<<<B / NB, BLOCK, 0, stream>>>(x, W_ih, W_hh, b_ih, b_hh, fc_w, fc_b, y);
}

// Round 4
// 705.148 us; speedup vs baseline: 2.5700x; 2.5700x over previous
//
#include <hip/hip_runtime.h>

// GRU fused, round 4 (= round 3 with the __fp16 vector-type fix).
// Thread = (batch bl 0..3, unit u 0..47), 192-thread blocks, 512 blocks.
// W_hh rows / W_ih rows / h / fc_w stored as packed f16 pairs; recurrent
// dot = 72 v_dot2_f32_f16 (fp32 accum) instead of 144 fp32 FMA -> weight
// regs halve (72) -> fits in VGPR file (round 1 spilled 144 to AGPR,
// round 2's occupancy push made the allocator demote weights to memory).
// gi is pipelined one step ahead (x loaded at step tail); h broadcast via
// LDS b128 reads (bank-disjoint quads); FC fused per 8-step window.

typedef __fp16 h2_t __attribute__((ext_vector_type(2)));

namespace {

constexpr int T = 1024;
constexpr int D = 6;
constexpr int H = 48;
constexpr int NB = 4;             // batches per block
constexpr int BLOCK = NB * H;     // 192 threads
constexpr int W = 8;              // h-history window for fused FC

__device__ __forceinline__ float fexp2(float x) { return __builtin_amdgcn_exp2f(x); }
__device__ __forceinline__ float frcp(float x) { return __builtin_amdgcn_rcpf(x); }
__device__ __forceinline__ float sigmoid_f(float x) {
  return frcp(1.0f + fexp2(-1.44269504088896340736f * x));
}
__device__ __forceinline__ float tanh_f(float x) {
  float e = fexp2(2.88539008177792681472f * x);
  return 1.0f - 2.0f * frcp(e + 1.0f);
}
__device__ __forceinline__ h2_t pk(float a, float b) {
  return __builtin_amdgcn_cvt_pkrtz(a, b);
}
__device__ __forceinline__ float fdot2(h2_t a, h2_t b, float c) {
  return __builtin_amdgcn_fdot2(a, b, c, false);
}
__device__ __forceinline__ h2_t bc(unsigned v) {
  union { unsigned u; h2_t h; } x; x.u = v; return x.h;
}

__global__ __launch_bounds__(BLOCK, 2) void gru_fused(
    const float* __restrict__ x, const float* __restrict__ W_ih,
    const float* __restrict__ W_hh, const float* __restrict__ b_ih,
    const float* __restrict__ b_hh, const float* __restrict__ fc_w,
    const float* __restrict__ fc_b, float* __restrict__ y) {

  // h as packed f16 pairs: 24 data dwords + 4 pad -> 7 uint4 per (slot,batch).
  // Row stride 28 dwords: bank quads for bl=0..3 at {0,28,24,20}+4j mod 32 ->
  // disjoint -> pure broadcast, conflict-free.
  __shared__ uint4 h2s[W][NB][7];
  __shared__ uint4 fcw2s[D][6];    // fc_w rows packed f16: 24 dwords each

  const int tid = threadIdx.x;
  const int bl  = tid / H;         // local batch 0..3
  const int u   = tid - bl * H;    // unit 0..47

  // zero h window (step 0 reads slot W-1)
  for (int i = tid; i < W * NB * 7 * 4; i += BLOCK)
    ((unsigned*)&h2s[0][0][0])[i] = 0u;
  // pack fc_w -> f16 pairs
  if (tid < D * 24) {
    const int d = tid / 24, j = tid - d * 24;
    const float2 w = ((const float2*)(fc_w + d * H))[j];
    ((h2_t*)&fcw2s[d][0])[j] = pk(w.x, w.y);
  }

  // own gate rows of W_hh (u: reset, u+H: update, u+2H: new) packed f16
  h2_t wr2[24], wz2[24], wn2[24];
  {
    const float2* rr = (const float2*)(W_hh + (u) * H);
    const float2* rz = (const float2*)(W_hh + (u + H) * H);
    const float2* rn = (const float2*)(W_hh + (u + 2 * H) * H);
#pragma unroll
    for (int j = 0; j < 24; ++j) {
      wr2[j] = pk(rr[j].x, rr[j].y);
      wz2[j] = pk(rz[j].x, rz[j].y);
      wn2[j] = pk(rn[j].x, rn[j].y);
    }
  }
  h2_t wir2[3], wiz2[3], win2[3];
  {
    const float2* rr = (const float2*)(W_ih + (u) * D);
    const float2* rz = (const float2*)(W_ih + (u + H) * D);
    const float2* rn = (const float2*)(W_ih + (u + 2 * H) * D);
#pragma unroll
    for (int j = 0; j < 3; ++j) {
      wir2[j] = pk(rr[j].x, rr[j].y);
      wiz2[j] = pk(rz[j].x, rz[j].y);
      win2[j] = pk(rn[j].x, rn[j].y);
    }
  }
  const float bias_r  = b_ih[u] + b_hh[u];
  const float bias_z  = b_ih[u + H] + b_hh[u + H];
  const float bias_gi = b_ih[u + 2 * H];
  const float bias_gh = b_hh[u + 2 * H];

  const size_t bB = (size_t)blockIdx.x * NB;

  // FC mapping: 192 threads = 4 batches x 8 timesteps x 6 outputs
  const int yb = tid / 48, rr_ = tid - yb * 48, yts = rr_ / D, yd = rr_ - yts * D;
  const float fcb = fc_b[yd];
  float* ybase = y + ((bB + yb) * (size_t)T + yts) * D + yd;

  const float2* xpp = (const float2*)(x + (bB + bl) * (size_t)T * D);

  __syncthreads();

  float hreg = 0.0f;
  // x[t=0] packed
  float2 a0 = xpp[0], a1 = xpp[1], a2 = xpp[2];
  h2_t x01 = pk(a0.x, a0.y), x23 = pk(a1.x, a1.y), x45 = pk(a2.x, a2.y);

  for (int t0 = 0; t0 < T; t0 += W) {
#pragma unroll
    for (int tw = 0; tw < W; ++tw) {
      const int t = t0 + tw;
      const int p = (tw + W - 1) & (W - 1);

      // issue h broadcast reads first (only post-barrier latency)
      const uint4* hv = &h2s[p][bl][0];
      const uint4 h0 = hv[0], h1 = hv[1], h2 = hv[2];
      const uint4 h3 = hv[3], h4 = hv[4], h5 = hv[5];

      // gi from pipelined x (no h dependency; covers ds_read latency)
      float rb = fdot2(wir2[0], x01, 0.0f);
      rb = fdot2(wir2[1], x23, rb);
      rb = fdot2(wir2[2], x45, rb);
      float zb = fdot2(wiz2[0], x01, 0.0f);
      zb = fdot2(wiz2[1], x23, zb);
      zb = fdot2(wiz2[2], x45, zb);
      float gi = fdot2(win2[0], x01, bias_gi);
      gi = fdot2(win2[1], x23, gi);
      gi = fdot2(win2[2], x45, gi);

      // recurrent dots: 72 fdot2, 6 chains (2 per gate)
      float ra = bias_r, za = bias_z, na = bias_gh, nb = 0.0f;
#define STEP4(hq, q)                                   \
      ra = fdot2(wr2[4*(q)+0], bc((hq).x), ra);        \
      za = fdot2(wz2[4*(q)+0], bc((hq).x), za);        \
      na = fdot2(wn2[4*(q)+0], bc((hq).x), na);        \
      rb = fdot2(wr2[4*(q)+1], bc((hq).y), rb);        \
      zb = fdot2(wz2[4*(q)+1], bc((hq).y), zb);        \
      nb = fdot2(wn2[4*(q)+1], bc((hq).y), nb);        \
      ra = fdot2(wr2[4*(q)+2], bc((hq).z), ra);        \
      za = fdot2(wz2[4*(q)+2], bc((hq).z), za);        \
      na = fdot2(wn2[4*(q)+2], bc((hq).z), na);        \
      rb = fdot2(wr2[4*(q)+3], bc((hq).w), rb);        \
      zb = fdot2(wz2[4*(q)+3], bc((hq).w), zb);        \
      nb = fdot2(wn2[4*(q)+3], bc((hq).w), nb);
      STEP4(h0, 0) STEP4(h1, 1) STEP4(h2, 2)
      STEP4(h3, 3) STEP4(h4, 4) STEP4(h5, 5)
#undef STEP4

      const float r  = sigmoid_f(ra + rb);
      const float zz = sigmoid_f(za + zb);
      const float n  = tanh_f(fmaf(r, na + nb, gi));
      hreg = fmaf(zz, hreg - n, n);   // (1-z)n + z h

      ((__fp16*)&h2s[tw][bl][0])[u] = (__fp16)hreg;

      // prefetch + pack x[t+1] (tail: overlaps with other waves' dots)
      const int tn = (t + 1 < T) ? (t + 1) : t;
      a0 = xpp[tn * 3 + 0]; a1 = xpp[tn * 3 + 1]; a2 = xpp[tn * 3 + 2];
      x01 = pk(a0.x, a0.y); x23 = pk(a1.x, a1.y); x45 = pk(a2.x, a2.y);

      __syncthreads();
    }

    // fused FC over the window: one output per thread (4b x 8t x 6d = 192)
    {
      const uint4* hv = &h2s[yts][yb][0];
      const uint4* fv = &fcw2s[yd][0];
      float f0 = fcb, f1 = 0.0f;
#pragma unroll
      for (int j = 0; j < 6; ++j) {
        const uint4 hh = hv[j], ww = fv[j];
        f0 = fdot2(bc(hh.x), bc(ww.x), f0);
        f1 = fdot2(bc(hh.y), bc(ww.y), f1);
        f0 = fdot2(bc(hh.z), bc(ww.z), f0);
        f1 = fdot2(bc(hh.w), bc(ww.w), f1);
      }
      ybase[t0 * D] = f0 + f1;
    }
    __syncthreads();  // protect h2s from next window's slot-0 write
  }
}

}  // namespace

extern "C" void kernel_launch(void* const* d_in, const int* in_sizes, int n_in,
                              void* d_out, int out_size, void* d_ws, size_t ws_size,
                              hipStream_t stream) {
  const float* x    = (const float*)d_in[0];
  const float* W_ih = (const float*)d_in[1];
  const float* W_hh = (const float*)d_in[2];
  const float* b_ih = (const float*)d_in[3];
  const float* b_hh = (const float*)d_in[4];
  const float* fc_w = (const float*)d_in[5];
  const float* fc_b = (const float*)d_in[6];
  float* y = (float*)d_out;

  constexpr int B = 2048;
  gru_fused<<<B / NB, BLOCK, 0, stream>>>(x, W_ih, W_hh, b_ih, b_hh, fc_w, fc_b, y);
}

// Round 5
// 693.466 us; speedup vs baseline: 2.6133x; 1.0168x over previous
//
#include <hip/hip_runtime.h>

// GRU fused, round 5: wave-per-batch, barrier-free.
// One 64-lane wave per batch (2048 blocks x 64 threads = 2 waves/SIMD even).
// All h exchange is wave-synchronous LDS (write h -> lgkmcnt -> broadcast
// read; lockstep wave, NO s_barrier). Round 4 lost 50% to per-step
// __syncthreads convoys at 1.5 ragged waves/SIMD.
// Math unchanged from round 4: f16 packed weights + v_dot2_f32_f16
// (72 fdot2 recurrent + 9 gi), fp32 accum, windowed FC every 8 steps.

typedef __fp16 h2_t __attribute__((ext_vector_type(2)));

namespace {

constexpr int T = 1024;
constexpr int D = 6;
constexpr int H = 48;
constexpr int W = 8;              // h-history window for fused FC

__device__ __forceinline__ float fexp2(float x) { return __builtin_amdgcn_exp2f(x); }
__device__ __forceinline__ float frcp(float x) { return __builtin_amdgcn_rcpf(x); }
__device__ __forceinline__ float sigmoid_f(float x) {
  return frcp(1.0f + fexp2(-1.44269504088896340736f * x));
}
__device__ __forceinline__ float tanh_f(float x) {
  float e = fexp2(2.88539008177792681472f * x);
  return 1.0f - 2.0f * frcp(e + 1.0f);
}
__device__ __forceinline__ h2_t pk(float a, float b) {
  return __builtin_amdgcn_cvt_pkrtz(a, b);
}
__device__ __forceinline__ float fdot2(h2_t a, h2_t b, float c) {
  return __builtin_amdgcn_fdot2(a, b, c, false);
}
__device__ __forceinline__ h2_t bc(unsigned v) {
  union { unsigned u; h2_t h; } x; x.u = v; return x.h;
}

__global__ __launch_bounds__(64, 2) void gru_fused(
    const float* __restrict__ x, const float* __restrict__ W_ih,
    const float* __restrict__ W_hh, const float* __restrict__ b_ih,
    const float* __restrict__ b_hh, const float* __restrict__ fc_w,
    const float* __restrict__ fc_b, float* __restrict__ y) {

  // One wave per block: LDS is wave-private, no barriers anywhere.
  // Slot stride 28 dwords -> slots hit distinct bank quads (FC phase);
  // recurrence reads are same-address broadcasts (conflict-free).
  __shared__ uint4 h2s[W][7];      // 48 f16 (24 dwords) + 4 pad per slot
  __shared__ uint4 fcw2s[D][7];    // fc_w rows packed f16, padded stride

  const int tid = threadIdx.x;     // 0..63
  const int u   = (tid < 48) ? tid : 47;   // clamp idle lanes (no OOB loads)
  const bool active = (tid < 48);

  // zero h window (step 0 reads slot W-1); pack fc_w
  for (int i = tid; i < W * 28; i += 64) ((unsigned*)&h2s[0][0])[i] = 0u;
  for (int i = tid; i < D * 24; i += 64) {
    const int d = i / 24, j = i - d * 24;
    const float2 w = ((const float2*)(fc_w + d * H))[j];
    ((h2_t*)&fcw2s[d][0])[j] = pk(w.x, w.y);
  }

  // own gate rows of W_hh (u: reset, u+H: update, u+2H: new) packed f16
  h2_t wr2[24], wz2[24], wn2[24];
  {
    const float2* rr = (const float2*)(W_hh + (u) * H);
    const float2* rz = (const float2*)(W_hh + (u + H) * H);
    const float2* rn = (const float2*)(W_hh + (u + 2 * H) * H);
#pragma unroll
    for (int j = 0; j < 24; ++j) {
      wr2[j] = pk(rr[j].x, rr[j].y);
      wz2[j] = pk(rz[j].x, rz[j].y);
      wn2[j] = pk(rn[j].x, rn[j].y);
    }
  }
  h2_t wir2[3], wiz2[3], win2[3];
  {
    const float2* rr = (const float2*)(W_ih + (u) * D);
    const float2* rz = (const float2*)(W_ih + (u + H) * D);
    const float2* rn = (const float2*)(W_ih + (u + 2 * H) * D);
#pragma unroll
    for (int j = 0; j < 3; ++j) {
      wir2[j] = pk(rr[j].x, rr[j].y);
      wiz2[j] = pk(rz[j].x, rz[j].y);
      win2[j] = pk(rn[j].x, rn[j].y);
    }
  }
  const float bias_r  = b_ih[u] + b_hh[u];
  const float bias_z  = b_ih[u + H] + b_hh[u + H];
  const float bias_gi = b_ih[u + 2 * H];
  const float bias_gh = b_hh[u + 2 * H];

  const size_t batch = blockIdx.x;

  // FC mapping: lanes 0..47 = 8 timesteps x 6 outputs
  const int yts = u / D, yd = u - yts * D;
  const float fcb = fc_b[yd];
  float* ybase = y + (batch * (size_t)T + yts) * D + yd;

  const float2* xpp = (const float2*)(x + batch * (size_t)T * D);

  float hreg = 0.0f;
  // x[t=0] packed (wave-uniform address -> broadcast load)
  float2 a0 = xpp[0], a1 = xpp[1], a2 = xpp[2];
  h2_t x01 = pk(a0.x, a0.y), x23 = pk(a1.x, a1.y), x45 = pk(a2.x, a2.y);

  __builtin_amdgcn_wave_barrier();   // LDS init complete before loop reads

  for (int t0 = 0; t0 < T; t0 += W) {
#pragma unroll
    for (int tw = 0; tw < W; ++tw) {
      const int t = t0 + tw;
      const int p = (tw + W - 1) & (W - 1);

      // h broadcast reads (same addr across lanes; wave-ordered vs the
      // ds_write at the previous step's tail)
      const uint4* hv = &h2s[p][0];
      const uint4 h0 = hv[0], h1 = hv[1], h2 = hv[2];
      const uint4 h3 = hv[3], h4 = hv[4], h5 = hv[5];

      // gi from pipelined x (no h dependency; covers ds_read latency)
      float rb = fdot2(wir2[0], x01, 0.0f);
      rb = fdot2(wir2[1], x23, rb);
      rb = fdot2(wir2[2], x45, rb);
      float zb = fdot2(wiz2[0], x01, 0.0f);
      zb = fdot2(wiz2[1], x23, zb);
      zb = fdot2(wiz2[2], x45, zb);
      float gi = fdot2(win2[0], x01, bias_gi);
      gi = fdot2(win2[1], x23, gi);
      gi = fdot2(win2[2], x45, gi);

      // recurrent dots: 72 fdot2, 6 chains
      float ra = bias_r, za = bias_z, na = bias_gh, nb = 0.0f;
#define STEP4(hq, q)                                   \
      ra = fdot2(wr2[4*(q)+0], bc((hq).x), ra);        \
      za = fdot2(wz2[4*(q)+0], bc((hq).x), za);        \
      na = fdot2(wn2[4*(q)+0], bc((hq).x), na);        \
      rb = fdot2(wr2[4*(q)+1], bc((hq).y), rb);        \
      zb = fdot2(wz2[4*(q)+1], bc((hq).y), zb);        \
      nb = fdot2(wn2[4*(q)+1], bc((hq).y), nb);        \
      ra = fdot2(wr2[4*(q)+2], bc((hq).z), ra);        \
      za = fdot2(wz2[4*(q)+2], bc((hq).z), za);        \
      na = fdot2(wn2[4*(q)+2], bc((hq).z), na);        \
      rb = fdot2(wr2[4*(q)+3], bc((hq).w), rb);        \
      zb = fdot2(wz2[4*(q)+3], bc((hq).w), zb);        \
      nb = fdot2(wn2[4*(q)+3], bc((hq).w), nb);
      STEP4(h0, 0) STEP4(h1, 1) STEP4(h2, 2)
      STEP4(h3, 3) STEP4(h4, 4) STEP4(h5, 5)
#undef STEP4

      const float r  = sigmoid_f(ra + rb);
      const float zz = sigmoid_f(za + zb);
      const float n  = tanh_f(fmaf(r, na + nb, gi));
      hreg = fmaf(zz, hreg - n, n);   // (1-z)n + z h

      if (active) ((__fp16*)&h2s[tw][0])[u] = (__fp16)hreg;
      __builtin_amdgcn_wave_barrier();  // keep write before next step's reads

      // prefetch + pack x[t+1]
      const int tn = (t + 1 < T) ? (t + 1) : t;
      a0 = xpp[tn * 3 + 0]; a1 = xpp[tn * 3 + 1]; a2 = xpp[tn * 3 + 2];
      x01 = pk(a0.x, a0.y); x23 = pk(a1.x, a1.y); x45 = pk(a2.x, a2.y);
    }

    // fused FC over the window: lanes 0..47 = 8 ts x 6 outs; slots and fcw
    // rows on disjoint bank quads (stride 28 dwords)
    if (active) {
      const uint4* hv = &h2s[yts][0];
      const uint4* fv = &fcw2s[yd][0];
      float f0 = fcb, f1 = 0.0f;
#pragma unroll
      for (int j = 0; j < 6; ++j) {
        const uint4 hh = hv[j], ww = fv[j];
        f0 = fdot2(bc(hh.x), bc(ww.x), f0);
        f1 = fdot2(bc(hh.y), bc(ww.y), f1);
        f0 = fdot2(bc(hh.z), bc(ww.z), f0);
        f1 = fdot2(bc(hh.w), bc(ww.w), f1);
      }
      ybase[t0 * D] = f0 + f1;
    }
    __builtin_amdgcn_wave_barrier();  // FC reads before next window's writes
  }
}

}  // namespace

extern "C" void kernel_launch(void* const* d_in, const int* in_sizes, int n_in,
                              void* d_out, int out_size, void* d_ws, size_t ws_size,
                              hipStream_t stream) {
  const float* x    = (const float*)d_in[0];
  const float* W_ih = (const float*)d_in[1];
  const float* W_hh = (const float*)d_in[2];
  const float* b_ih = (const float*)d_in[3];
  const float* b_hh = (const float*)d_in[4];
  const float* fc_w = (const float*)d_in[5];
  const float* fc_b = (const float*)d_in[6];
  float* y = (float*)d_out;

  constexpr int B = 2048;
  gru_fused<<<B, 64, 0, stream>>>(x, W_ih, W_hh, b_ih, b_hh, fc_w, fc_b, y);
}

// Round 6
// 687.976 us; speedup vs baseline: 2.6342x; 1.0080x over previous
//
#include <hip/hip_runtime.h>

// GRU fused, round 6: round 5 + amdgpu_waves_per_eu(2,2).
// Round 5 forensics: wall 1624 cyc/step/SIMD, busy 67% -> ~272 VALU
// inst/step/wave vs ~110 in source; VGPR_Count=68 vs ~135 live dwords
// needed. The allocator squeezed regs for its own occupancy target
// (launch_bounds min-waves is only a floor), demoting the f16 weight
// arrays to AGPR/scratch with a copy per use. Grid gives exactly
// 2 waves/SIMD, so cap max waves at 2 -> 256-reg budget -> weights stay
// in arch VGPRs. Code otherwise identical to round 5.

typedef __fp16 h2_t __attribute__((ext_vector_type(2)));

namespace {

constexpr int T = 1024;
constexpr int D = 6;
constexpr int H = 48;
constexpr int W = 8;              // h-history window for fused FC

__device__ __forceinline__ float fexp2(float x) { return __builtin_amdgcn_exp2f(x); }
__device__ __forceinline__ float frcp(float x) { return __builtin_amdgcn_rcpf(x); }
__device__ __forceinline__ float sigmoid_f(float x) {
  return frcp(1.0f + fexp2(-1.44269504088896340736f * x));
}
__device__ __forceinline__ float tanh_f(float x) {
  float e = fexp2(2.88539008177792681472f * x);
  return 1.0f - 2.0f * frcp(e + 1.0f);
}
__device__ __forceinline__ h2_t pk(float a, float b) {
  return __builtin_amdgcn_cvt_pkrtz(a, b);
}
__device__ __forceinline__ float fdot2(h2_t a, h2_t b, float c) {
  return __builtin_amdgcn_fdot2(a, b, c, false);
}
__device__ __forceinline__ h2_t bc(unsigned v) {
  union { unsigned u; h2_t h; } x; x.u = v; return x.h;
}

__global__ __launch_bounds__(64)
__attribute__((amdgpu_waves_per_eu(2, 2)))
void gru_fused(
    const float* __restrict__ x, const float* __restrict__ W_ih,
    const float* __restrict__ W_hh, const float* __restrict__ b_ih,
    const float* __restrict__ b_hh, const float* __restrict__ fc_w,
    const float* __restrict__ fc_b, float* __restrict__ y) {

  // One wave per block: LDS is wave-private, no barriers anywhere.
  // Slot stride 28 dwords -> slots hit distinct bank quads (FC phase);
  // recurrence reads are same-address broadcasts (conflict-free).
  __shared__ uint4 h2s[W][7];      // 48 f16 (24 dwords) + 4 pad per slot
  __shared__ uint4 fcw2s[D][7];    // fc_w rows packed f16, padded stride

  const int tid = threadIdx.x;     // 0..63
  const int u   = (tid < 48) ? tid : 47;   // clamp idle lanes (no OOB loads)
  const bool active = (tid < 48);

  // zero h window (step 0 reads slot W-1); pack fc_w
  for (int i = tid; i < W * 28; i += 64) ((unsigned*)&h2s[0][0])[i] = 0u;
  for (int i = tid; i < D * 24; i += 64) {
    const int d = i / 24, j = i - d * 24;
    const float2 w = ((const float2*)(fc_w + d * H))[j];
    ((h2_t*)&fcw2s[d][0])[j] = pk(w.x, w.y);
  }

  // own gate rows of W_hh (u: reset, u+H: update, u+2H: new) packed f16
  h2_t wr2[24], wz2[24], wn2[24];
  {
    const float2* rr = (const float2*)(W_hh + (u) * H);
    const float2* rz = (const float2*)(W_hh + (u + H) * H);
    const float2* rn = (const float2*)(W_hh + (u + 2 * H) * H);
#pragma unroll
    for (int j = 0; j < 24; ++j) {
      wr2[j] = pk(rr[j].x, rr[j].y);
      wz2[j] = pk(rz[j].x, rz[j].y);
      wn2[j] = pk(rn[j].x, rn[j].y);
    }
  }
  h2_t wir2[3], wiz2[3], win2[3];
  {
    const float2* rr = (const float2*)(W_ih + (u) * D);
    const float2* rz = (const float2*)(W_ih + (u + H) * D);
    const float2* rn = (const float2*)(W_ih + (u + 2 * H) * D);
#pragma unroll
    for (int j = 0; j < 3; ++j) {
      wir2[j] = pk(rr[j].x, rr[j].y);
      wiz2[j] = pk(rz[j].x, rz[j].y);
      win2[j] = pk(rn[j].x, rn[j].y);
    }
  }
  const float bias_r  = b_ih[u] + b_hh[u];
  const float bias_z  = b_ih[u + H] + b_hh[u + H];
  const float bias_gi = b_ih[u + 2 * H];
  const float bias_gh = b_hh[u + 2 * H];

  const size_t batch = blockIdx.x;

  // FC mapping: lanes 0..47 = 8 timesteps x 6 outputs
  const int yts = u / D, yd = u - yts * D;
  const float fcb = fc_b[yd];
  float* ybase = y + (batch * (size_t)T + yts) * D + yd;

  const float2* xpp = (const float2*)(x + batch * (size_t)T * D);

  float hreg = 0.0f;
  // x[t=0] packed (wave-uniform address -> broadcast load)
  float2 a0 = xpp[0], a1 = xpp[1], a2 = xpp[2];
  h2_t x01 = pk(a0.x, a0.y), x23 = pk(a1.x, a1.y), x45 = pk(a2.x, a2.y);

  __builtin_amdgcn_wave_barrier();   // LDS init complete before loop reads

  for (int t0 = 0; t0 < T; t0 += W) {
#pragma unroll
    for (int tw = 0; tw < W; ++tw) {
      const int t = t0 + tw;
      const int p = (tw + W - 1) & (W - 1);

      // h broadcast reads (same addr across lanes; wave-ordered vs the
      // ds_write at the previous step's tail)
      const uint4* hv = &h2s[p][0];
      const uint4 h0 = hv[0], h1 = hv[1], h2 = hv[2];
      const uint4 h3 = hv[3], h4 = hv[4], h5 = hv[5];

      // gi from pipelined x (no h dependency; covers ds_read latency)
      float rb = fdot2(wir2[0], x01, 0.0f);
      rb = fdot2(wir2[1], x23, rb);
      rb = fdot2(wir2[2], x45, rb);
      float zb = fdot2(wiz2[0], x01, 0.0f);
      zb = fdot2(wiz2[1], x23, zb);
      zb = fdot2(wiz2[2], x45, zb);
      float gi = fdot2(win2[0], x01, bias_gi);
      gi = fdot2(win2[1], x23, gi);
      gi = fdot2(win2[2], x45, gi);

      // recurrent dots: 72 fdot2, 6 chains
      float ra = bias_r, za = bias_z, na = bias_gh, nb = 0.0f;
#define STEP4(hq, q)                                   \
      ra = fdot2(wr2[4*(q)+0], bc((hq).x), ra);        \
      za = fdot2(wz2[4*(q)+0], bc((hq).x), za);        \
      na = fdot2(wn2[4*(q)+0], bc((hq).x), na);        \
      rb = fdot2(wr2[4*(q)+1], bc((hq).y), rb);        \
      zb = fdot2(wz2[4*(q)+1], bc((hq).y), zb);        \
      nb = fdot2(wn2[4*(q)+1], bc((hq).y), nb);        \
      ra = fdot2(wr2[4*(q)+2], bc((hq).z), ra);        \
      za = fdot2(wz2[4*(q)+2], bc((hq).z), za);        \
      na = fdot2(wn2[4*(q)+2], bc((hq).z), na);        \
      rb = fdot2(wr2[4*(q)+3], bc((hq).w), rb);        \
      zb = fdot2(wz2[4*(q)+3], bc((hq).w), zb);        \
      nb = fdot2(wn2[4*(q)+3], bc((hq).w), nb);
      STEP4(h0, 0) STEP4(h1, 1) STEP4(h2, 2)
      STEP4(h3, 3) STEP4(h4, 4) STEP4(h5, 5)
#undef STEP4

      const float r  = sigmoid_f(ra + rb);
      const float zz = sigmoid_f(za + zb);
      const float n  = tanh_f(fmaf(r, na + nb, gi));
      hreg = fmaf(zz, hreg - n, n);   // (1-z)n + z h

      if (active) ((__fp16*)&h2s[tw][0])[u] = (__fp16)hreg;
      __builtin_amdgcn_wave_barrier();  // keep write before next step's reads

      // prefetch + pack x[t+1]
      const int tn = (t + 1 < T) ? (t + 1) : t;
      a0 = xpp[tn * 3 + 0]; a1 = xpp[tn * 3 + 1]; a2 = xpp[tn * 3 + 2];
      x01 = pk(a0.x, a0.y); x23 = pk(a1.x, a1.y); x45 = pk(a2.x, a2.y);
    }

    // fused FC over the window: lanes 0..47 = 8 ts x 6 outs; slots and fcw
    // rows on disjoint bank quads (stride 28 dwords)
    if (active) {
      const uint4* hv = &h2s[yts][0];
      const uint4* fv = &fcw2s[yd][0];
      float f0 = fcb, f1 = 0.0f;
#pragma unroll
      for (int j = 0; j < 6; ++j) {
        const uint4 hh = hv[j], ww = fv[j];
        f0 = fdot2(bc(hh.x), bc(ww.x), f0);
        f1 = fdot2(bc(hh.y), bc(ww.y), f1);
        f0 = fdot2(bc(hh.z), bc(ww.z), f0);
        f1 = fdot2(bc(hh.w), bc(ww.w), f1);
      }
      ybase[t0 * D] = f0 + f1;
    }
    __builtin_amdgcn_wave_barrier();  // FC reads before next window's writes
  }
}

}  // namespace

extern "C" void kernel_launch(void* const* d_in, const int* in_sizes, int n_in,
                              void* d_out, int out_size, void* d_ws, size_t ws_size,
                              hipStream_t stream) {
  const float* x    = (const float*)d_in[0];
  const float* W_ih = (const float*)d_in[1];
  const float* W_hh = (const float*)d_in[2];
  const float* b_ih = (const float*)d_in[3];
  const float* b_hh = (const float*)d_in[4];
  const float* fc_w = (const float*)d_in[5];
  const float* fc_b = (const float*)d_in[6];
  float* y = (float*)d_out;

  constexpr int B = 2048;
  gru_fused<<<B, 64, 0, stream>>>(x, W_ih, W_hh, b_ih, b_hh, fc_w, fc_b, y);
}